// Round 10
// baseline (175.328 us; speedup 1.0000x reference)
//
#include <hip/hip_runtime.h>
#include <hip/hip_bf16.h>
#include <math.h>
#include <type_traits>

using s16x8 = __attribute__((ext_vector_type(8))) short;
using s16x4 = __attribute__((ext_vector_type(4))) short;
using f32x4 = __attribute__((ext_vector_type(4))) float;
using f32x16 = __attribute__((ext_vector_type(16))) float;
using u32 = unsigned int;
using u32x4 = __attribute__((ext_vector_type(4))) u32;

static __device__ __forceinline__ short f2bf(float f) {
  union { float f; unsigned u; } v; v.f = f;
  unsigned r = v.u + 0x7fff + ((v.u >> 16) & 1);   // RNE
  return (short)(r >> 16);
}

static __device__ __forceinline__ unsigned cvt_pk_bf16(float lo, float hi) {
  unsigned r;
  asm("v_cvt_pk_bf16_f32 %0, %1, %2" : "=v"(r) : "v"(lo), "v"(hi));
  return r;
}

#define GLOAD_LDS(gsrc, ldst)                                                      \
  __builtin_amdgcn_global_load_lds(                                                \
      (const __attribute__((address_space(1))) void*)(gsrc),                       \
      (__attribute__((address_space(3))) void*)(ldst), 16, 0, 0)

// ---------------- cast f32 -> bf16 (vectorized) ----------------
__global__ void cast_f32_bf16(const float* __restrict__ in, short* __restrict__ out, int n4) {
  int i = blockIdx.x * blockDim.x + threadIdx.x;
  int stride = gridDim.x * blockDim.x;
  for (int idx = i; idx < n4; idx += stride) {
    float4 v = reinterpret_cast<const float4*>(in)[idx];
    s16x4 o; o[0] = f2bf(v.x); o[1] = f2bf(v.y); o[2] = f2bf(v.z); o[3] = f2bf(v.w);
    reinterpret_cast<s16x4*>(out)[idx] = o;
  }
}

// ---------------- transpose + cast: in[R][C] f32 -> out[C][R] bf16 ----------------
__global__ void transpose_cast(const float* __restrict__ in, short* __restrict__ out, int R, int C) {
  __shared__ float tile[32][33];
  int cb = blockIdx.x * 32, rb = blockIdx.y * 32;
  int tx = threadIdx.x, ty = threadIdx.y;  // block (32, 8)
  #pragma unroll
  for (int i = 0; i < 32; i += 8)
    tile[ty + i][tx] = in[(size_t)(rb + ty + i) * C + cb + tx];
  __syncthreads();
  #pragma unroll
  for (int i = 0; i < 32; i += 8)
    out[(size_t)(cb + ty + i) * R + rb + tx] = f2bf(tile[tx][ty + i]);
}

// ---- bf16 MFMA GEMM v2: C[M][N] = A[M][K] * BT[N][K]^T.
// 128x128 tile, 4 waves (2x2 of 64x64), BK=64, double-buffered XOR-swizzled LDS
// (chunk^(row&7), staged via pre-swizzled global source), ONE barrier per K-step
// (2-phase: stage(t+1) issued before compute(t), drained at next barrier).
// XCD-aware block swizzle. VFUSE: cols >= 2048 written transposed into vt.
template <typename OutT, bool VFUSE>
__global__ __launch_bounds__(256) void gemm_bt(const short* __restrict__ A,
                                               const short* __restrict__ BT,
                                               OutT* __restrict__ C,
                                               short* __restrict__ vtOut,
                                               int M, int N, int K, int ldc) {
  __shared__ __align__(16) short As[2][128 * 64];
  __shared__ __align__(16) short Bs[2][128 * 64];
  const int t = threadIdx.x;
  const int lane = t & 63, wid = t >> 6;
  const int wm = wid >> 1, wn = wid & 1;           // 2x2 waves, 64x64 each
  const int lr = lane & 15, lg = lane >> 4;

  // XCD-aware swizzle (nwg % 8 == 0 for all our launches)
  const int gx = gridDim.x;
  const int nwg = gx * gridDim.y;
  int fid = blockIdx.y * gx + blockIdx.x;
  fid = (fid & 7) * (nwg >> 3) + (fid >> 3);
  const int bn = (fid % gx) * 128;
  const int bm = (fid / gx) * 128;

  // staging source: lane covers 8 rows x 8 chunks; source chunk pre-swizzled
  const int srow = lane >> 3;                      // 0..7
  const int schunk = (lane & 7) ^ srow;            // involution
  const short* ap = A + (size_t)(bm + wid * 8 + srow) * K + schunk * 8;
  const short* bp = BT + (size_t)(bn + wid * 8 + srow) * K + schunk * 8;

  f32x4 acc[4][4] = {};
  const int nk = K >> 6;

  auto stage = [&](int buf, int kt) {
    const size_t ko = (size_t)kt << 6;
    #pragma unroll
    for (int j = 0; j < 4; ++j) {
      GLOAD_LDS(ap + (size_t)j * 32 * K + ko, &As[buf][(j * 32 + wid * 8) * 64]);
      GLOAD_LDS(bp + (size_t)j * 32 * K + ko, &Bs[buf][(j * 32 + wid * 8) * 64]);
    }
  };

  stage(0, 0);
  for (int kt = 0; kt < nk; ++kt) {
    __syncthreads();                       // prev reads done; buf[kt&1] loads landed
    if (kt + 1 < nk) stage((kt + 1) & 1, kt + 1);
    const short* A_ = &As[kt & 1][0];
    const short* B_ = &Bs[kt & 1][0];
    #pragma unroll
    for (int ks = 0; ks < 2; ++ks) {
      s16x8 af[4], bfr[4];
      #pragma unroll
      for (int i = 0; i < 4; ++i) {
        int r = wm * 64 + i * 16 + lr;
        af[i] = *reinterpret_cast<const s16x8*>(&A_[r * 64 + (((ks * 4 + lg) ^ (r & 7)) * 8)]);
      }
      #pragma unroll
      for (int j = 0; j < 4; ++j) {
        int r = wn * 64 + j * 16 + lr;
        bfr[j] = *reinterpret_cast<const s16x8*>(&B_[r * 64 + (((ks * 4 + lg) ^ (r & 7)) * 8)]);
      }
      #pragma unroll
      for (int i = 0; i < 4; ++i)
        #pragma unroll
        for (int j = 0; j < 4; ++j)
          acc[i][j] = __builtin_amdgcn_mfma_f32_16x16x32_bf16(af[i], bfr[j], acc[i][j], 0, 0, 0);
    }
  }

  const int r0 = bm + wm * 64, c0 = bn + wn * 64;
  if (!VFUSE || c0 < 2048) {
    #pragma unroll
    for (int i = 0; i < 4; ++i)
      #pragma unroll
      for (int j = 0; j < 4; ++j)
        #pragma unroll
        for (int r = 0; r < 4; ++r) {
          int row = r0 + i * 16 + lg * 4 + r;
          int col = c0 + j * 16 + lr;
          float v = acc[i][j][r];
          if constexpr (std::is_same<OutT, short>::value)
            C[(size_t)row * ldc + col] = f2bf(v);
          else
            C[(size_t)row * ldc + col] = v;
        }
  } else {
    const int bb = bm >> 11;                       // batch index (block never straddles)
    #pragma unroll
    for (int i = 0; i < 4; ++i) {
      int tok = (bm & 2047) + wm * 64 + i * 16 + lg * 4;
      #pragma unroll
      for (int j = 0; j < 4; ++j) {
        int col = c0 + j * 16 + lr;                // 2048..3071
        s16x4 p;
        #pragma unroll
        for (int r = 0; r < 4; ++r) p[r] = f2bf(acc[i][j][r]);
        *reinterpret_cast<s16x4*>(vtOut + (size_t)(bb * 1024 + col - 2048) * 2048 + tok) = p;
      }
    }
  }
}

// ---------------- flash attention: 4 waves x 32 q-rows, 32x32 MFMA, swapped operands ----
// 3-deep K/V LDS pipeline with COUNTED vmcnt (never drain-to-0 in the loop) and
// split barriers: barrier#1 guards buffer overwrite, barrier#2 guards "everyone's
// tile-t loads landed" (each wave waits its own vmcnt before it). Loads get ~2
// compute phases to cover L3/HBM latency.
__global__ __launch_bounds__(256, 3) void attn_kernel(const short* __restrict__ qk,
                                                      const short* __restrict__ vt,
                                                      short* __restrict__ att) {
  const int T = 2048, C2 = 2048, Cc = 1024;
  const int fid = blockIdx.x;
  const int qb = 15 - (fid >> 6);            // global LPT: heavy (qb=15) blocks first
  const int bh = fid & 63;
  const int h = bh & 15, b = bh >> 4;
  const int t = threadIdx.x;
  const int w = t >> 6, l = t & 63;
  const int q2 = l & 31, hi = l >> 5;

  __shared__ __align__(16) short Ks[3][64 * 64];   // [key][d], chunk-swizzled
  __shared__ __align__(16) short Vts[3][64 * 64];  // [d][key], chunk-swizzled

  const int qrow_base = qb * 128 + w * 32;
  const int qrow = qrow_base + q2;
  const int tmax = 2 * qb + (w >> 1);        // last active tile index for this wave
  const int nt = 2 * qb + 2;

  // Q B-fragments (col=lane&31=q, k=d), pre-scaled by 0.125*log2(e)
  const float SC = 0.125f * 1.44269504088896340736f;
  s16x8 aq[4];
  #pragma unroll
  for (int ds = 0; ds < 4; ++ds) {
    s16x8 q = *reinterpret_cast<const s16x8*>(
        qk + (size_t)(b * T + qrow) * C2 + h * 64 + ds * 16 + hi * 8);
    #pragma unroll
    for (int j = 0; j < 8; ++j) {
      union { float f; unsigned u; } v; v.u = ((unsigned)(unsigned short)q[j]) << 16;
      q[j] = f2bf(v.f * SC);
    }
    aq[ds] = q;
  }

  f32x16 o[2] = {};                  // O^T: [d][q], col=lane&31=q
  float mst = -INFINITY, lst = 0.f;  // scalar per lane (q = q2)

  const int srow = w * 16 + (l >> 3);
  const int srcc8 = ((l & 7) ^ (l >> 3)) * 8;
  const short* kp = qk + (size_t)(b * T + srow) * C2 + Cc + h * 64 + srcc8;
  const short* vp = vt + (size_t)(bh * 64 + srow) * T + srcc8;

  auto stage = [&](int buf) {
    GLOAD_LDS(kp,           &Ks[buf][(w * 16) * 64]);
    GLOAD_LDS(kp + 8 * C2,  &Ks[buf][(w * 16 + 8) * 64]);
    GLOAD_LDS(vp,           &Vts[buf][(w * 16) * 64]);
    GLOAD_LDS(vp + 8 * T,   &Vts[buf][(w * 16 + 8) * 64]);
    kp += 64 * C2;
    vp += 64;
  };

  stage(0);
  if (nt > 1) stage(1);
  for (int tt = 0; tt < nt; ++tt) {
    // barrier#1: all waves done reading buf[(tt+2)%3] (their compute(tt-1))
    __builtin_amdgcn_s_barrier();
    if (tt + 2 < nt) stage((tt + 2) % 3);
    // counted wait: my stage(tt) landed (2 younger stages stay in flight)
    if (tt + 2 < nt)      asm volatile("s_waitcnt vmcnt(8)" ::: "memory");
    else if (tt + 1 < nt) asm volatile("s_waitcnt vmcnt(4)" ::: "memory");
    else                  asm volatile("s_waitcnt vmcnt(0)" ::: "memory");
    // barrier#2: every wave has waited its own stage(tt) -> whole tile resident
    __builtin_amdgcn_s_barrier();
    __builtin_amdgcn_sched_barrier(0);
    if (tt > tmax) continue;
    const int j0 = tt << 6;
    const short* K_ = &Ks[tt % 3][0];
    const short* V_ = &Vts[tt % 3][0];

    // ---- swapped QK^T: S^T[key][q] ----
    f32x16 st[2];
    __builtin_amdgcn_s_setprio(1);
    #pragma unroll
    for (int kt = 0; kt < 2; ++kt) {
      f32x16 s = {};
      #pragma unroll
      for (int ds = 0; ds < 4; ++ds) {
        int row = kt * 32 + q2;
        s16x8 ak = *reinterpret_cast<const s16x8*>(
            &K_[row * 64 + (((ds * 2 + hi) ^ (row & 7)) * 8)]);
        s = __builtin_amdgcn_mfma_f32_32x32x16_bf16(ak, aq[ds], s, 0, 0, 0);
      }
      st[kt] = s;
    }
    __builtin_amdgcn_s_setprio(0);

    // ---- causal mask (diagonal tiles only) ----
    if (j0 + 63 > qrow_base) {
      #pragma unroll
      for (int kt = 0; kt < 2; ++kt)
        #pragma unroll
        for (int r = 0; r < 16; ++r) {
          int key = j0 + kt * 32 + (r & 3) + 8 * (r >> 2) + 4 * hi;
          if (key > qrow) st[kt][r] = -INFINITY;
        }
    }

    // ---- online softmax (exp2 domain, defer-max THR=8) ----
    float a16[16];
    #pragma unroll
    for (int r = 0; r < 16; ++r) a16[r] = fmaxf(st[0][r], st[1][r]);
    #pragma unroll
    for (int r = 0; r < 8; ++r) a16[r] = fmaxf(a16[r], a16[r + 8]);
    #pragma unroll
    for (int r = 0; r < 4; ++r) a16[r] = fmaxf(a16[r], a16[r + 4]);
    float mx = fmaxf(fmaxf(a16[0], a16[1]), fmaxf(a16[2], a16[3]));
    mx = fmaxf(mx, __shfl_xor(mx, 32));
    const bool resc = !__all(mx - mst <= 8.f);   // P bounded by 2^8 otherwise
    if (resc) {
      float mn = fmaxf(mst, mx);
      float corr = exp2f(mst - mn);              // first tile: exp2(-inf)=0
      mst = mn;
      lst *= corr;
      #pragma unroll
      for (int dt = 0; dt < 2; ++dt)
        #pragma unroll
        for (int r = 0; r < 16; ++r) o[dt][r] *= corr;
    }
    #pragma unroll
    for (int kt = 0; kt < 2; ++kt)
      #pragma unroll
      for (int r = 0; r < 16; ++r) st[kt][r] = exp2f(st[kt][r] - mst);
    float sv[16];
    #pragma unroll
    for (int r = 0; r < 16; ++r) sv[r] = st[0][r] + st[1][r];
    #pragma unroll
    for (int r = 0; r < 8; ++r) sv[r] += sv[r + 8];
    #pragma unroll
    for (int r = 0; r < 4; ++r) sv[r] += sv[r + 4];
    float ps = (sv[0] + sv[1]) + (sv[2] + sv[3]);
    ps += __shfl_xor(ps, 32);
    lst += ps;

    // ---- repack P^T -> B-fragments: cvt_pk + permlane32_swap ----
    s16x8 pb[4];
    #pragma unroll
    for (int kt = 0; kt < 2; ++kt)
      #pragma unroll
      for (int s = 0; s < 2; ++s) {
        unsigned w01 = cvt_pk_bf16(st[kt][s * 8 + 0], st[kt][s * 8 + 1]);
        unsigned w23 = cvt_pk_bf16(st[kt][s * 8 + 2], st[kt][s * 8 + 3]);
        unsigned w45 = cvt_pk_bf16(st[kt][s * 8 + 4], st[kt][s * 8 + 5]);
        unsigned w67 = cvt_pk_bf16(st[kt][s * 8 + 6], st[kt][s * 8 + 7]);
        asm("v_permlane32_swap_b32 %0, %1" : "+v"(w01), "+v"(w45));
        asm("v_permlane32_swap_b32 %0, %1" : "+v"(w23), "+v"(w67));
        u32x4 f; f[0] = w01; f[1] = w23; f[2] = w45; f[3] = w67;
        pb[kt * 2 + s] = *reinterpret_cast<s16x8*>(&f);
      }

    // ---- swapped PV: O^T[d][q] += V^T[d][k] * P^T[k][q] ----
    __builtin_amdgcn_s_setprio(1);
    #pragma unroll
    for (int dt = 0; dt < 2; ++dt) {
      int row = dt * 32 + q2;
      #pragma unroll
      for (int ks = 0; ks < 4; ++ks) {
        s16x8 av = *reinterpret_cast<const s16x8*>(
            &V_[row * 64 + (((ks * 2 + hi) ^ (row & 7)) * 8)]);
        o[dt] = __builtin_amdgcn_mfma_f32_32x32x16_bf16(av, pb[ks], o[dt], 0, 0, 0);
      }
    }
    __builtin_amdgcn_s_setprio(0);
  }

  // ---- epilogue: O^T -> att[token][C] via swizzled per-wave LDS transpose ----
  __syncthreads();
  u32* osm = reinterpret_cast<u32*>(&Ks[0][0]) + w * 1024;  // 4KB per wave
  float inv = 1.f / lst;
  #pragma unroll
  for (int dt = 0; dt < 2; ++dt)
    #pragma unroll
    for (int p = 0; p < 8; ++p) {
      unsigned pk = ((unsigned)(unsigned short)f2bf(o[dt][2 * p + 1] * inv) << 16)
                  | (unsigned)(unsigned short)f2bf(o[dt][2 * p] * inv);
      int col = dt * 16 + (p >> 1) * 4 + 2 * hi + (p & 1);   // u32 col = d/2
      int chunk = col >> 2, inc = col & 3;
      osm[q2 * 32 + ((chunk ^ (q2 & 7)) * 4) + inc] = pk;
    }
  #pragma unroll
  for (int c = 0; c < 4; ++c) {
    int chunk = hi * 4 + c;
    u32x4 v4 = *reinterpret_cast<u32x4*>(&osm[q2 * 32 + ((chunk ^ (q2 & 7)) * 4)]);
    *reinterpret_cast<u32x4*>(
        att + (size_t)(b * T + qrow_base + q2) * Cc + h * 64 + chunk * 8) = v4;
  }
}

extern "C" void kernel_launch(void* const* d_in, const int* in_sizes, int n_in,
                              void* d_out, int out_size, void* d_ws, size_t ws_size,
                              hipStream_t stream) {
  const float* x     = (const float*)d_in[0];   // [4,2048,1024]
  const float* w_qkv = (const float*)d_in[1];   // [1024,3072]
  const float* w_out = (const float*)d_in[2];   // [1024,1024]
  float* out = (float*)d_out;                   // [4,2048,1024]

  char* ws = (char*)d_ws;
  short* xb    = (short*)(ws);                        // 16,777,216
  short* wqkvT = (short*)(ws + 16777216);             //  6,291,456
  short* woT   = (short*)(ws + 23068672);             //  2,097,152
  short* qk    = (short*)(ws + 25165824);             // 33,554,432  [8192][2048]
  short* vtb   = (short*)(ws + 58720256);             // 16,777,216  [4096][2048]
  short* att   = (short*)(ws + 75497472);             // 16,777,216  -> total 92,274,688

  cast_f32_bf16<<<2048, 256, 0, stream>>>(x, xb, (8192 * 1024) / 4);
  transpose_cast<<<dim3(3072 / 32, 1024 / 32), dim3(32, 8), 0, stream>>>(w_qkv, wqkvT, 1024, 3072);
  transpose_cast<<<dim3(1024 / 32, 1024 / 32), dim3(32, 8), 0, stream>>>(w_out, woT, 1024, 1024);

  gemm_bt<short, true><<<dim3(3072 / 128, 8192 / 128), 256, 0, stream>>>(
      xb, wqkvT, qk, vtb, 8192, 3072, 1024, 2048);
  attn_kernel<<<1024, 256, 0, stream>>>(qk, vtb, att);
  gemm_bt<float, false><<<dim3(1024 / 128, 8192 / 128), 256, 0, stream>>>(
      att, woT, out, nullptr, 8192, 1024, 1024, 1024);
}

// Round 11
// 161.890 us; speedup vs baseline: 1.0830x; 1.0830x over previous
//
#include <hip/hip_runtime.h>
#include <hip/hip_bf16.h>
#include <math.h>
#include <type_traits>

using s16x8 = __attribute__((ext_vector_type(8))) short;
using s16x4 = __attribute__((ext_vector_type(4))) short;
using f32x4 = __attribute__((ext_vector_type(4))) float;
using f32x16 = __attribute__((ext_vector_type(16))) float;
using u32 = unsigned int;
using u32x4 = __attribute__((ext_vector_type(4))) u32;

static __device__ __forceinline__ short f2bf(float f) {
  union { float f; unsigned u; } v; v.f = f;
  unsigned r = v.u + 0x7fff + ((v.u >> 16) & 1);   // RNE
  return (short)(r >> 16);
}

static __device__ __forceinline__ unsigned cvt_pk_bf16(float lo, float hi) {
  unsigned r;
  asm("v_cvt_pk_bf16_f32 %0, %1, %2" : "=v"(r) : "v"(lo), "v"(hi));
  return r;
}

// raw v_exp_f32 (exp2). Single-in/single-out: no operand-coalescing hazard.
static __device__ __forceinline__ float fast_exp2(float x) {
  float r; asm("v_exp_f32 %0, %1" : "=v"(r) : "v"(x)); return r;
}

#define GLOAD_LDS(gsrc, ldst)                                                      \
  __builtin_amdgcn_global_load_lds(                                                \
      (const __attribute__((address_space(1))) void*)(gsrc),                       \
      (__attribute__((address_space(3))) void*)(ldst), 16, 0, 0)

// ---------------- cast f32 -> bf16 (vectorized) ----------------
__global__ void cast_f32_bf16(const float* __restrict__ in, short* __restrict__ out, int n4) {
  int i = blockIdx.x * blockDim.x + threadIdx.x;
  int stride = gridDim.x * blockDim.x;
  for (int idx = i; idx < n4; idx += stride) {
    float4 v = reinterpret_cast<const float4*>(in)[idx];
    s16x4 o; o[0] = f2bf(v.x); o[1] = f2bf(v.y); o[2] = f2bf(v.z); o[3] = f2bf(v.w);
    reinterpret_cast<s16x4*>(out)[idx] = o;
  }
}

// ---------------- transpose + cast: in[R][C] f32 -> out[C][R] bf16 ----------------
__global__ void transpose_cast(const float* __restrict__ in, short* __restrict__ out, int R, int C) {
  __shared__ float tile[32][33];
  int cb = blockIdx.x * 32, rb = blockIdx.y * 32;
  int tx = threadIdx.x, ty = threadIdx.y;  // block (32, 8)
  #pragma unroll
  for (int i = 0; i < 32; i += 8)
    tile[ty + i][tx] = in[(size_t)(rb + ty + i) * C + cb + tx];
  __syncthreads();
  #pragma unroll
  for (int i = 0; i < 32; i += 8)
    out[(size_t)(cb + ty + i) * R + rb + tx] = f2bf(tile[tx][ty + i]);
}

// ---- bf16 MFMA GEMM v2: C[M][N] = A[M][K] * BT[N][K]^T.
// 128x128 tile, 4 waves (2x2 of 64x64), BK=64, double-buffered XOR-swizzled LDS,
// ONE barrier per K-step, XCD-aware block swizzle. VFUSE: cols >= 2048 written
// transposed into vt.
template <typename OutT, bool VFUSE>
__global__ __launch_bounds__(256) void gemm_bt(const short* __restrict__ A,
                                               const short* __restrict__ BT,
                                               OutT* __restrict__ C,
                                               short* __restrict__ vtOut,
                                               int M, int N, int K, int ldc) {
  __shared__ __align__(16) short As[2][128 * 64];
  __shared__ __align__(16) short Bs[2][128 * 64];
  const int t = threadIdx.x;
  const int lane = t & 63, wid = t >> 6;
  const int wm = wid >> 1, wn = wid & 1;           // 2x2 waves, 64x64 each
  const int lr = lane & 15, lg = lane >> 4;

  // XCD-aware swizzle (nwg % 8 == 0 for all our launches)
  const int gx = gridDim.x;
  const int nwg = gx * gridDim.y;
  int fid = blockIdx.y * gx + blockIdx.x;
  fid = (fid & 7) * (nwg >> 3) + (fid >> 3);
  const int bn = (fid % gx) * 128;
  const int bm = (fid / gx) * 128;

  // staging source: lane covers 8 rows x 8 chunks; source chunk pre-swizzled
  const int srow = lane >> 3;                      // 0..7
  const int schunk = (lane & 7) ^ srow;            // involution
  const short* ap = A + (size_t)(bm + wid * 8 + srow) * K + schunk * 8;
  const short* bp = BT + (size_t)(bn + wid * 8 + srow) * K + schunk * 8;

  f32x4 acc[4][4] = {};
  const int nk = K >> 6;

  auto stage = [&](int buf, int kt) {
    const size_t ko = (size_t)kt << 6;
    #pragma unroll
    for (int j = 0; j < 4; ++j) {
      GLOAD_LDS(ap + (size_t)j * 32 * K + ko, &As[buf][(j * 32 + wid * 8) * 64]);
      GLOAD_LDS(bp + (size_t)j * 32 * K + ko, &Bs[buf][(j * 32 + wid * 8) * 64]);
    }
  };

  stage(0, 0);
  for (int kt = 0; kt < nk; ++kt) {
    __syncthreads();                       // prev reads done; buf[kt&1] loads landed
    if (kt + 1 < nk) stage((kt + 1) & 1, kt + 1);
    const short* A_ = &As[kt & 1][0];
    const short* B_ = &Bs[kt & 1][0];
    #pragma unroll
    for (int ks = 0; ks < 2; ++ks) {
      s16x8 af[4], bfr[4];
      #pragma unroll
      for (int i = 0; i < 4; ++i) {
        int r = wm * 64 + i * 16 + lr;
        af[i] = *reinterpret_cast<const s16x8*>(&A_[r * 64 + (((ks * 4 + lg) ^ (r & 7)) * 8)]);
      }
      #pragma unroll
      for (int j = 0; j < 4; ++j) {
        int r = wn * 64 + j * 16 + lr;
        bfr[j] = *reinterpret_cast<const s16x8*>(&B_[r * 64 + (((ks * 4 + lg) ^ (r & 7)) * 8)]);
      }
      #pragma unroll
      for (int i = 0; i < 4; ++i)
        #pragma unroll
        for (int j = 0; j < 4; ++j)
          acc[i][j] = __builtin_amdgcn_mfma_f32_16x16x32_bf16(af[i], bfr[j], acc[i][j], 0, 0, 0);
    }
  }

  const int r0 = bm + wm * 64, c0 = bn + wn * 64;
  if (!VFUSE || c0 < 2048) {
    #pragma unroll
    for (int i = 0; i < 4; ++i)
      #pragma unroll
      for (int j = 0; j < 4; ++j)
        #pragma unroll
        for (int r = 0; r < 4; ++r) {
          int row = r0 + i * 16 + lg * 4 + r;
          int col = c0 + j * 16 + lr;
          float v = acc[i][j][r];
          if constexpr (std::is_same<OutT, short>::value)
            C[(size_t)row * ldc + col] = f2bf(v);
          else
            C[(size_t)row * ldc + col] = v;
        }
  } else {
    const int bb = bm >> 11;                       // batch index (block never straddles)
    #pragma unroll
    for (int i = 0; i < 4; ++i) {
      int tok = (bm & 2047) + wm * 64 + i * 16 + lg * 4;
      #pragma unroll
      for (int j = 0; j < 4; ++j) {
        int col = c0 + j * 16 + lr;                // 2048..3071
        s16x4 p;
        #pragma unroll
        for (int r = 0; r < 4; ++r) p[r] = f2bf(acc[i][j][r]);
        *reinterpret_cast<s16x4*>(vtOut + (size_t)(bb * 1024 + col - 2048) * 2048 + tok) = p;
      }
    }
  }
}

// ---------------- flash attention: 4 waves x 32 q-rows, 32x32 MFMA, swapped operands ----
// R9 2-buffer structure + raw v_exp_f32 + hoisted loop-invariant LDS fragment
// offsets (identical for K and V reads) + permlane repack + defer-max.
__global__ __launch_bounds__(256, 3) void attn_kernel(const short* __restrict__ qk,
                                                      const short* __restrict__ vt,
                                                      short* __restrict__ att) {
  const int T = 2048, C2 = 2048, Cc = 1024;
  const int fid = blockIdx.x;
  const int qb = 15 - (fid >> 6);            // global LPT: heavy (qb=15) blocks first
  const int bh = fid & 63;
  const int h = bh & 15, b = bh >> 4;
  const int t = threadIdx.x;
  const int w = t >> 6, l = t & 63;
  const int q2 = l & 31, hi = l >> 5;

  __shared__ __align__(16) short Ks[2][64 * 64];   // [key][d], chunk-swizzled
  __shared__ __align__(16) short Vts[2][64 * 64];  // [d][key], chunk-swizzled

  const int qrow_base = qb * 128 + w * 32;
  const int qrow = qrow_base + q2;
  const int tmax = 2 * qb + (w >> 1);        // last active tile index for this wave
  const int nt = 2 * qb + 2;

  // Q B-fragments (col=lane&31=q, k=d), pre-scaled by 0.125*log2(e)
  const float SC = 0.125f * 1.44269504088896340736f;
  s16x8 aq[4];
  #pragma unroll
  for (int ds = 0; ds < 4; ++ds) {
    s16x8 q = *reinterpret_cast<const s16x8*>(
        qk + (size_t)(b * T + qrow) * C2 + h * 64 + ds * 16 + hi * 8);
    #pragma unroll
    for (int j = 0; j < 8; ++j) {
      union { float f; unsigned u; } v; v.u = ((unsigned)(unsigned short)q[j]) << 16;
      q[j] = f2bf(v.f * SC);
    }
    aq[ds] = q;
  }

  // hoisted LDS fragment byte-offsets: off[g*4+i] = (g*32+q2)*128 + (((i*2+hi)^(q2&7))*16)
  // (same table serves the K reads [g=kt,i=ds] and the V reads [g=dt,i=ks])
  u32 off[8];
  #pragma unroll
  for (int g = 0; g < 2; ++g)
    #pragma unroll
    for (int i = 0; i < 4; ++i)
      off[g * 4 + i] = (u32)((g * 32 + q2) * 128 + (((i * 2 + hi) ^ (q2 & 7)) * 16));

  f32x16 o[2] = {};                  // O^T: [d][q], col=lane&31=q
  float mst = -INFINITY, lst = 0.f;  // scalar per lane (q = q2)

  const int srow = w * 16 + (l >> 3);
  const int srcc8 = ((l & 7) ^ (l >> 3)) * 8;
  const short* kp = qk + (size_t)(b * T + srow) * C2 + Cc + h * 64 + srcc8;
  const short* vp = vt + (size_t)(bh * 64 + srow) * T + srcc8;

  auto stage = [&](int buf) {
    GLOAD_LDS(kp,           &Ks[buf][(w * 16) * 64]);
    GLOAD_LDS(kp + 8 * C2,  &Ks[buf][(w * 16 + 8) * 64]);
    GLOAD_LDS(vp,           &Vts[buf][(w * 16) * 64]);
    GLOAD_LDS(vp + 8 * T,   &Vts[buf][(w * 16 + 8) * 64]);
    kp += 64 * C2;
    vp += 64;
  };

  stage(0);
  for (int tt = 0; tt < nt; ++tt) {
    __syncthreads();                   // buf[tt&1] ready; prev reads done
    if (tt + 1 < nt) stage((tt + 1) & 1);
    if (tt > tmax) continue;
    const int j0 = tt << 6;
    const char* K_ = reinterpret_cast<const char*>(&Ks[tt & 1][0]);
    const char* V_ = reinterpret_cast<const char*>(&Vts[tt & 1][0]);

    // ---- swapped QK^T: S^T[key][q] ----
    f32x16 st[2];
    __builtin_amdgcn_s_setprio(1);
    #pragma unroll
    for (int kt = 0; kt < 2; ++kt) {
      f32x16 s = {};
      #pragma unroll
      for (int ds = 0; ds < 4; ++ds) {
        s16x8 ak = *reinterpret_cast<const s16x8*>(K_ + off[kt * 4 + ds]);
        s = __builtin_amdgcn_mfma_f32_32x32x16_bf16(ak, aq[ds], s, 0, 0, 0);
      }
      st[kt] = s;
    }
    __builtin_amdgcn_s_setprio(0);

    // ---- causal mask (diagonal tiles only) ----
    if (j0 + 63 > qrow_base) {
      #pragma unroll
      for (int kt = 0; kt < 2; ++kt)
        #pragma unroll
        for (int r = 0; r < 16; ++r) {
          int key = j0 + kt * 32 + (r & 3) + 8 * (r >> 2) + 4 * hi;
          if (key > qrow) st[kt][r] = -INFINITY;
        }
    }

    // ---- online softmax (exp2 domain, defer-max THR=8) ----
    float a16[16];
    #pragma unroll
    for (int r = 0; r < 16; ++r) a16[r] = fmaxf(st[0][r], st[1][r]);
    #pragma unroll
    for (int r = 0; r < 8; ++r) a16[r] = fmaxf(a16[r], a16[r + 8]);
    #pragma unroll
    for (int r = 0; r < 4; ++r) a16[r] = fmaxf(a16[r], a16[r + 4]);
    float mx = fmaxf(fmaxf(a16[0], a16[1]), fmaxf(a16[2], a16[3]));
    mx = fmaxf(mx, __shfl_xor(mx, 32));
    const bool resc = !__all(mx - mst <= 8.f);   // P bounded by 2^8 otherwise
    if (resc) {
      float mn = fmaxf(mst, mx);
      float corr = fast_exp2(mst - mn);          // first tile: exp2(-inf)=0
      mst = mn;
      lst *= corr;
      #pragma unroll
      for (int dt = 0; dt < 2; ++dt)
        #pragma unroll
        for (int r = 0; r < 16; ++r) o[dt][r] *= corr;
    }
    #pragma unroll
    for (int kt = 0; kt < 2; ++kt)
      #pragma unroll
      for (int r = 0; r < 16; ++r) st[kt][r] = fast_exp2(st[kt][r] - mst);
    float sv[16];
    #pragma unroll
    for (int r = 0; r < 16; ++r) sv[r] = st[0][r] + st[1][r];
    #pragma unroll
    for (int r = 0; r < 8; ++r) sv[r] += sv[r + 8];
    #pragma unroll
    for (int r = 0; r < 4; ++r) sv[r] += sv[r + 4];
    float ps = (sv[0] + sv[1]) + (sv[2] + sv[3]);
    ps += __shfl_xor(ps, 32);
    lst += ps;

    // ---- repack P^T -> B-fragments: cvt_pk + permlane32_swap ----
    s16x8 pb[4];
    #pragma unroll
    for (int kt = 0; kt < 2; ++kt)
      #pragma unroll
      for (int s = 0; s < 2; ++s) {
        unsigned w01 = cvt_pk_bf16(st[kt][s * 8 + 0], st[kt][s * 8 + 1]);
        unsigned w23 = cvt_pk_bf16(st[kt][s * 8 + 2], st[kt][s * 8 + 3]);
        unsigned w45 = cvt_pk_bf16(st[kt][s * 8 + 4], st[kt][s * 8 + 5]);
        unsigned w67 = cvt_pk_bf16(st[kt][s * 8 + 6], st[kt][s * 8 + 7]);
        asm("v_permlane32_swap_b32 %0, %1" : "+v"(w01), "+v"(w45));
        asm("v_permlane32_swap_b32 %0, %1" : "+v"(w23), "+v"(w67));
        u32x4 f; f[0] = w01; f[1] = w23; f[2] = w45; f[3] = w67;
        pb[kt * 2 + s] = *reinterpret_cast<s16x8*>(&f);
      }

    // ---- swapped PV: O^T[d][q] += V^T[d][k] * P^T[k][q] ----
    __builtin_amdgcn_s_setprio(1);
    #pragma unroll
    for (int dt = 0; dt < 2; ++dt) {
      #pragma unroll
      for (int ks = 0; ks < 4; ++ks) {
        s16x8 av = *reinterpret_cast<const s16x8*>(V_ + off[dt * 4 + ks]);
        o[dt] = __builtin_amdgcn_mfma_f32_32x32x16_bf16(av, pb[ks], o[dt], 0, 0, 0);
      }
    }
    __builtin_amdgcn_s_setprio(0);
  }

  // ---- epilogue: O^T -> att[token][C] via swizzled per-wave LDS transpose ----
  __syncthreads();
  u32* osm = reinterpret_cast<u32*>(&Ks[0][0]) + w * 1024;  // 4KB per wave
  float inv = 1.f / lst;
  #pragma unroll
  for (int dt = 0; dt < 2; ++dt)
    #pragma unroll
    for (int p = 0; p < 8; ++p) {
      unsigned pk = ((unsigned)(unsigned short)f2bf(o[dt][2 * p + 1] * inv) << 16)
                  | (unsigned)(unsigned short)f2bf(o[dt][2 * p] * inv);
      int col = dt * 16 + (p >> 1) * 4 + 2 * hi + (p & 1);   // u32 col = d/2
      int chunk = col >> 2, inc = col & 3;
      osm[q2 * 32 + ((chunk ^ (q2 & 7)) * 4) + inc] = pk;
    }
  #pragma unroll
  for (int c = 0; c < 4; ++c) {
    int chunk = hi * 4 + c;
    u32x4 v4 = *reinterpret_cast<u32x4*>(&osm[q2 * 32 + ((chunk ^ (q2 & 7)) * 4)]);
    *reinterpret_cast<u32x4*>(
        att + (size_t)(b * T + qrow_base + q2) * Cc + h * 64 + chunk * 8) = v4;
  }
}

extern "C" void kernel_launch(void* const* d_in, const int* in_sizes, int n_in,
                              void* d_out, int out_size, void* d_ws, size_t ws_size,
                              hipStream_t stream) {
  const float* x     = (const float*)d_in[0];   // [4,2048,1024]
  const float* w_qkv = (const float*)d_in[1];   // [1024,3072]
  const float* w_out = (const float*)d_in[2];   // [1024,1024]
  float* out = (float*)d_out;                   // [4,2048,1024]

  char* ws = (char*)d_ws;
  short* xb    = (short*)(ws);                        // 16,777,216
  short* wqkvT = (short*)(ws + 16777216);             //  6,291,456
  short* woT   = (short*)(ws + 23068672);             //  2,097,152
  short* qk    = (short*)(ws + 25165824);             // 33,554,432  [8192][2048]
  short* vtb   = (short*)(ws + 58720256);             // 16,777,216  [4096][2048]
  short* att   = (short*)(ws + 75497472);             // 16,777,216  -> total 92,274,688

  cast_f32_bf16<<<2048, 256, 0, stream>>>(x, xb, (8192 * 1024) / 4);
  transpose_cast<<<dim3(3072 / 32, 1024 / 32), dim3(32, 8), 0, stream>>>(w_qkv, wqkvT, 1024, 3072);
  transpose_cast<<<dim3(1024 / 32, 1024 / 32), dim3(32, 8), 0, stream>>>(w_out, woT, 1024, 1024);

  gemm_bt<short, true><<<dim3(3072 / 128, 8192 / 128), 256, 0, stream>>>(
      xb, wqkvT, qk, vtb, 8192, 3072, 1024, 2048);
  attn_kernel<<<1024, 256, 0, stream>>>(qk, vtb, att);
  gemm_bt<float, false><<<dim3(1024 / 128, 8192 / 128), 256, 0, stream>>>(
      att, woT, out, nullptr, 8192, 1024, 1024, 1024);
}